// Round 15
// baseline (69.346 us; speedup 1.0000x reference)
//
#include <hip/hip_runtime.h>

typedef __attribute__((ext_vector_type(8))) short short8;
typedef __attribute__((ext_vector_type(4))) short short4v;
typedef __attribute__((ext_vector_type(4))) float f32x4;
typedef __attribute__((ext_vector_type(16))) float f32x16;
typedef __attribute__((ext_vector_type(4))) unsigned int uint4v;
typedef __attribute__((ext_vector_type(2))) unsigned int uint2v;
typedef unsigned short us;
typedef unsigned int u32;

#define NB 4
#define NC 64
#define NN 4096
#define ND 64
#define LOG2E 1.44269504088896340736f

static __device__ __forceinline__ us f2bf(float x) {
    u32 u = __builtin_bit_cast(u32, x);
    u += 0x7FFFu + ((u >> 16) & 1u);
    return (us)(u >> 16);
}

static __device__ __forceinline__ float bf2f(us v) {
    u32 u = ((u32)v) << 16;
    return __builtin_bit_cast(float, u);
}

static __device__ __forceinline__ u32 cvtpk(float a, float b) {
    u32 r;
    asm("v_cvt_pk_bf16_f32 %0, %1, %2" : "=v"(r) : "v"(a), "v"(b));
    return r;
}

static __device__ __forceinline__ short8 comb(short4v a, short4v b) {
    short8 r;
    r[0] = a[0]; r[1] = a[1]; r[2] = a[2]; r[3] = a[3];
    r[4] = b[0]; r[5] = b[1]; r[6] = b[2]; r[7] = b[3];
    return r;
}

static __device__ __forceinline__ void async_copy16(void* lds, const void* g) {
    __builtin_amdgcn_global_load_lds(
        (const __attribute__((address_space(1))) u32*)g,
        (__attribute__((address_space(3))) u32*)lds, 16, 0, 0);
}

static __device__ __forceinline__ int swz8(int row) {
    return (row & 7) ^ ((row >> 3) & 3);
}

// ---------------- kernel 1: weights -> bf16 (Wq pre-scaled by log2 e) ----------------
__global__ void cvt_kernel(const float* __restrict__ Wo,
                           const float* __restrict__ Wq,
                           const float* __restrict__ Wk,
                           const float* __restrict__ Wv,
                           us* __restrict__ Wob, us* __restrict__ Wqb,
                           us* __restrict__ Wkb, us* __restrict__ Wvb) {
    int i = blockIdx.x * 256 + threadIdx.x;
    if (i < 8192) Wob[i] = f2bf(Wo[i]);
    else if (i < 12288) Wqb[i - 8192] = f2bf(Wq[i - 8192] * LOG2E);
    else if (i < 16384) Wkb[i - 12288] = f2bf(Wk[i - 12288]);
    else if (i < 20480) Wvb[i - 16384] = f2bf(Wv[i - 16384]);
}

// ---------------- kernel 2: projections via MFMA (single-pass: Q,K,V,Xbt per block) ----------------
__global__ __launch_bounds__(256) void proj_kernel(
    const float* __restrict__ x,
    const us* __restrict__ Wqb, const float* __restrict__ bq,
    const us* __restrict__ Wkb, const float* __restrict__ bk,
    const us* __restrict__ Wvb, const float* __restrict__ bv,
    us* __restrict__ Qt, us* __restrict__ Kt,
    us* __restrict__ Vm, us* __restrict__ Xbt)
{
    __shared__ float xs[64][64];                 // [c][n] fp32
    __shared__ __align__(16) us xT[64][64];      // [n][c] bf16, XOR-swizzled
    const int t = threadIdx.x;
    const int v = blockIdx.x;
    const int b = v >> 6;
    const int n0 = (v & 63) << 6;
    const float* xb = x + (size_t)b * NC * NN + n0;
    #pragma unroll
    for (int i = 0; i < 4; ++i) {
        int s = t + i * 256;
        int c = s >> 4, col = (s & 15) << 2;
        *(f32x4*)&xs[c][col] = *(const f32x4*)&xb[(size_t)c * NN + col];
    }
    __syncthreads();
    {
        int n = t & 63, cg = t >> 6;
        int c0 = cg << 4;
        u32 pk[8];
        #pragma unroll
        for (int j = 0; j < 8; ++j) {
            float a0 = xs[c0 + 2 * j][n], a1 = xs[c0 + 2 * j + 1][n];
            pk[j] = (u32)f2bf(a0) | ((u32)f2bf(a1) << 16);
        }
        int b0 = (cg * 2) ^ (n & 7), b1 = (cg * 2 + 1) ^ (n & 7);
        *(uint4v*)&xT[n][b0 * 8] = (uint4v){pk[0], pk[1], pk[2], pk[3]};
        *(uint4v*)&xT[n][b1 * 8] = (uint4v){pk[4], pk[5], pk[6], pk[7]};
        us* dst = Xbt + (size_t)(b * NN + n0 + n) * ND + c0;
        *(uint4v*)dst       = (uint4v){pk[0], pk[1], pk[2], pk[3]};
        *(uint4v*)(dst + 8) = (uint4v){pk[4], pk[5], pk[6], pk[7]};
    }
    __syncthreads();
    const int w = t >> 6, l = t & 63, h = l >> 4, ln = l & 15;
    const int row = w * 16 + ln;
    short8 xq0 = *(const short8*)&xT[row][((h ^ (row & 7)) << 3)];
    short8 xq1 = *(const short8*)&xT[row][(((4 + h) ^ (row & 7)) << 3)];

    #pragma unroll
    for (int p = 0; p < 2; ++p) {
        const us* Wb = p ? Wkb : Wqb;
        const float* bias = p ? bk : bq;
        const float sc = p ? 1.0f : LOG2E;
        us* outp = p ? Kt : Qt;
        #pragma unroll
        for (int di = 0; di < 4; ++di) {
            const int d = di * 16 + ln;
            const us* wrb = Wb + (size_t)d * 64;
            short8 a0 = *(const short8*)(wrb + h * 8);
            short8 a1 = *(const short8*)(wrb + 32 + h * 8);
            f32x4 acc = *(const f32x4*)(bias + di * 16 + h * 4);
            acc *= sc;
            acc = __builtin_amdgcn_mfma_f32_16x16x32_bf16(a0, xq0, acc, 0, 0, 0);
            acc = __builtin_amdgcn_mfma_f32_16x16x32_bf16(a1, xq1, acc, 0, 0, 0);
            u32 lo = (u32)f2bf(acc[0]) | ((u32)f2bf(acc[1]) << 16);
            u32 hi2 = (u32)f2bf(acc[2]) | ((u32)f2bf(acc[3]) << 16);
            *(uint2v*)(outp + (size_t)(b * NN + n0 + row) * ND + di * 16 + h * 4) = (uint2v){lo, hi2};
        }
    }
    #pragma unroll
    for (int di = 0; di < 4; ++di) {
        const int d = di * 16 + ln;
        const us* wrb = Wvb + (size_t)d * 64;
        short8 a0 = *(const short8*)(wrb + h * 8);
        short8 a1 = *(const short8*)(wrb + 32 + h * 8);
        f32x4 acc = *(const f32x4*)(bv + di * 16 + h * 4);
        acc = __builtin_amdgcn_mfma_f32_16x16x32_bf16(a0, xq0, acc, 0, 0, 0);
        acc = __builtin_amdgcn_mfma_f32_16x16x32_bf16(a1, xq1, acc, 0, 0, 0);
        us* vp = Vm + (size_t)(b * ND + di * 16 + h * 4) * NN + n0 + row;
        vp[0] = f2bf(acc[0]); vp[NN] = f2bf(acc[1]);
        vp[2 * NN] = f2bf(acc[2]); vp[3 * NN] = f2bf(acc[3]);
    }
}

// ---------------- kernel 3: flash attention partials (4 waves, full 64-m tile per wave-iter) ----------------
static __device__ __forceinline__ void mask_bounds32(int pt, int n032, int ng,
    int& lo_n, int& hi_n, int& lo_min, int& lo_max, int& hi_min, int& hi_max)
{
    if (pt == 0)      { lo_n = 0;           hi_n = ng;          lo_min = 0;              lo_max = 0;             hi_min = n032;           hi_max = n032 + 31; }
    else if (pt == 1) { lo_n = NN - 1 - ng; hi_n = NN - 1;      lo_min = NN - 32 - n032; lo_max = NN - 1 - n032; hi_min = NN - 1;         hi_max = NN - 1; }
    else if (pt == 2) { lo_n = ng;          hi_n = NN - 1;      lo_min = n032;           lo_max = n032 + 31;     hi_min = NN - 1;         hi_max = NN - 1; }
    else if (pt == 3) { lo_n = 0;           hi_n = NN - 1 - ng; lo_min = 0;              lo_max = 0;             hi_min = NN - 32 - n032; hi_max = NN - 1 - n032; }
    else              { lo_n = 0;           hi_n = NN - 1;      lo_min = 0;              lo_max = 0;             hi_min = NN - 1;         hi_max = NN - 1; }
}

__global__ __launch_bounds__(256, 4) void attn_kernel(
    const us* __restrict__ Qt, const us* __restrict__ Kt,
    const us* __restrict__ Vm,
    const int* __restrict__ ordp,
    u32* __restrict__ Opk, float* __restrict__ Lb)
{
    // 32KB: K [2 bufs][64m x 64d], V [2 bufs][64d x 64m]; swz8 16B-block swizzle
    __shared__ __align__(16) us Kl[2][64 * 64];
    __shared__ __align__(16) us Vl[2][64 * 64];

    const int tid = threadIdx.x;
    const int w = tid >> 6, l = tid & 63;
    const int hi = l >> 5, ln = l & 31;
    const int nh = w;                             // 4 q-quarters; each wave owns full 64-m tile
    const int bid = blockIdx.x;
    const int vid = (bid & 7) * 64 + (bid >> 3);  // bijective XCD swizzle (512 = 8*64)
    const int b = vid >> 7;
    const int ms = (vid >> 5) & 3;                // block-level m-quarter
    const int qt = vid & 31;
    const int n0 = qt << 7;                       // 128-q block tile
    const int mbase = ms << 10;                   // 1024-m quarter
    const int n032 = n0 + nh * 32;
    const int ng = n032 + ln;

    const int ord = ordp[0];
    int pt = 4;
    if (ord == 1) pt = 0;
    else if (ord == 2 || ord == 3) pt = 1;
    else if (ord == 4 || ord == 5 || ord == 8) pt = 2;
    else if (ord == 6 || ord == 7) pt = 3;
    int lo_n, hi_n, lo_min, lo_max, hi_min, hi_max;
    mask_bounds32(pt, n032, ng, lo_n, hi_n, lo_min, lo_max, hi_min, hi_max);

    const us* kb = Kt + (size_t)b * NN * ND;
    const us* vb = Vm + (size_t)b * ND * NN;
    const us* qrow = Qt + (size_t)(b * NN + n032 + ln) * ND;
    short8 qf0 = *(const short8*)(qrow + 0 * 16 + hi * 8);
    short8 qf1 = *(const short8*)(qrow + 1 * 16 + hi * 8);
    short8 qf2 = *(const short8*)(qrow + 2 * 16 + hi * 8);
    short8 qf3 = *(const short8*)(qrow + 3 * 16 + hi * 8);

    f32x16 O0, O1, Z;
    #pragma unroll
    for (int i = 0; i < 16; ++i) { O0[i] = 0.f; O1[i] = 0.f; Z[i] = 0.f; }
    float Lp = 0.f;

    // staging (r6/r8-proven): waves 0,1 stage K row-halves; waves 2,3 stage V d-halves.
    // 4 async_copy16 (4KB)/wave/tile, unconditional (uniform vmcnt).
    auto stage = [&](int buf, int t) {
        const int m_base = mbase + t * 64;
        if (w < 2) {
            #pragma unroll
            for (int r = 0; r < 4; ++r) {
                const int rl = w * 32 + r * 8 + (l >> 3);
                const int blk = l & 7;
                const us* src = kb + (size_t)(m_base + rl) * ND + ((blk ^ swz8(rl)) << 3);
                async_copy16(&Kl[buf][(w * 32 + r * 8) * 64], src);
            }
        } else {
            #pragma unroll
            for (int r = 0; r < 4; ++r) {
                const int rl = (w - 2) * 32 + r * 8 + (l >> 3);
                const int blk = l & 7;
                const us* src = vb + (size_t)rl * NN + m_base + ((blk ^ swz8(rl)) << 3);
                async_copy16(&Vl[buf][((w - 2) * 32 + r * 8) * 64], src);
            }
        }
    };

    stage(0, 0);
    for (int t = 0; t < 16; ++t) {
        if (t < 15) {
            stage((t + 1) & 1, t + 1);
            asm volatile("s_waitcnt vmcnt(4)" ::: "memory");
        } else {
            asm volatile("s_waitcnt vmcnt(0)" ::: "memory");
        }
        __builtin_amdgcn_s_barrier();
        __builtin_amdgcn_sched_barrier(0);

        const us* KT = Kl[t & 1];
        const us* VT = Vl[t & 1];

        __builtin_amdgcn_s_setprio(1);
        #pragma unroll
        for (int s01 = 0; s01 < 2; ++s01) {
            const int m0s = mbase + t * 64 + s01 * 32;
            const bool skip = (m0s + 31 < lo_min) || (m0s > hi_max);
            const bool full = (m0s >= lo_max) && (m0s + 31 <= hi_min);

            const int row = s01 * 32 + ln;
            const int rs = swz8(row);
            short8 a0 = *(const short8*)&KT[row * 64 + (((0 + hi) ^ rs) << 3)];
            short8 a1 = *(const short8*)&KT[row * 64 + (((2 + hi) ^ rs) << 3)];
            short8 a2 = *(const short8*)&KT[row * 64 + (((4 + hi) ^ rs) << 3)];
            short8 a3 = *(const short8*)&KT[row * 64 + (((6 + hi) ^ rs) << 3)];
            // two independent 2-deep QK chains
            f32x16 st0 = __builtin_amdgcn_mfma_f32_32x32x16_bf16(a0, qf0, Z, 0, 0, 0);
            f32x16 st1 = __builtin_amdgcn_mfma_f32_32x32x16_bf16(a2, qf2, Z, 0, 0, 0);
            st0 = __builtin_amdgcn_mfma_f32_32x32x16_bf16(a1, qf1, st0, 0, 0, 0);
            st1 = __builtin_amdgcn_mfma_f32_32x32x16_bf16(a3, qf3, st1, 0, 0, 0);

            float p[16];
            float lp0 = 0.f, lp1 = 0.f;
            #pragma unroll
            for (int r = 0; r < 16; ++r) {
                p[r] = __builtin_amdgcn_exp2f(st0[r] + st1[r]);  // no max-subtraction: |logit| small
                if (r & 1) lp1 += p[r]; else lp0 += p[r];
            }
            Lp += lp0 + lp1;
            if (!skip) {
                if (!full) {
                    #pragma unroll
                    for (int r = 0; r < 16; ++r) {
                        const int mg = m0s + (r & 3) + 8 * (r >> 2) + 4 * hi;
                        if (mg < lo_n || mg > hi_n) p[r] = 0.f;
                    }
                }
                #pragma unroll
                for (int c16 = 0; c16 < 2; ++c16) {
                    uint4v pw;
                    pw[0] = cvtpk(p[c16 * 8 + 0], p[c16 * 8 + 1]);
                    pw[1] = cvtpk(p[c16 * 8 + 2], p[c16 * 8 + 3]);
                    pw[2] = cvtpk(p[c16 * 8 + 4], p[c16 * 8 + 5]);
                    pw[3] = cvtpk(p[c16 * 8 + 6], p[c16 * 8 + 7]);
                    short8 pb = __builtin_bit_cast(short8, pw);
                    const int blkA = s01 * 4 + c16 * 2;
                    {
                        const int rv = ln, rvs = swz8(rv);
                        short4v va  = *(const short4v*)&VT[rv * 64 + ((blkA ^ rvs) << 3) + hi * 4];
                        short4v vb2 = *(const short4v*)&VT[rv * 64 + (((blkA + 1) ^ rvs) << 3) + hi * 4];
                        O0 = __builtin_amdgcn_mfma_f32_32x32x16_bf16(comb(va, vb2), pb, O0, 0, 0, 0);
                    }
                    {
                        const int rv = 32 + ln, rvs = swz8(rv);
                        short4v va  = *(const short4v*)&VT[rv * 64 + ((blkA ^ rvs) << 3) + hi * 4];
                        short4v vb2 = *(const short4v*)&VT[rv * 64 + (((blkA + 1) ^ rvs) << 3) + hi * 4];
                        O1 = __builtin_amdgcn_mfma_f32_32x32x16_bf16(comb(va, vb2), pb, O1, 0, 0, 0);
                    }
                }
            }
        }
        __builtin_amdgcn_s_setprio(0);
        __builtin_amdgcn_sched_barrier(0);
        __builtin_amdgcn_s_barrier();
    }

    // ---- no in-block combine needed: each wave owns its full (q32, m-quarter) tile ----
    float Lw = Lp + __shfl_xor(Lp, 32);

    // write unnormalized bf16-pair-packed partials: Opk [4 ms][B][32 dpair][N] u32
    u32* opk = Opk + ((size_t)(ms * NB + b) * 32) * NN + n032 + ln;
    #pragma unroll
    for (int rp = 0; rp < 16; rp += 2) {
        const int dp = ((rp & 3) >> 1) + 4 * (rp >> 2) + 2 * hi;   // d0(rp)/2
        opk[(size_t)dp * NN] = cvtpk(O0[rp], O0[rp + 1]);
        opk[(size_t)(dp + 16) * NN] = cvtpk(O1[rp], O1[rp + 1]);
    }
    if (hi == 0) Lb[(size_t)(ms * NB + b) * NN + n032 + ln] = Lw;
}

// ---------------- kernel 4: combine partials + fused output conv (512 x 1-wave) ----------------
__global__ __launch_bounds__(64) void combine_kernel(
    const u32* __restrict__ Opk, const float* __restrict__ Lb,
    const us* __restrict__ Xbt, const us* __restrict__ Wob,
    const float* __restrict__ bo, float* __restrict__ out)
{
    const int l = threadIdx.x, hi = l >> 5, ln = l & 31;
    const int gw = blockIdx.x;
    const int b = gw >> 7;
    const int n032 = (gw & 127) << 5;
    const int q = n032 + ln;

    f32x16 On0, On1;
    #pragma unroll
    for (int i = 0; i < 16; ++i) { On0[i] = 0.f; On1[i] = 0.f; }
    #pragma unroll
    for (int part = 0; part < 4; ++part) {
        const u32* pb = Opk + ((size_t)(part * NB + b) * 32) * NN + q;
        #pragma unroll
        for (int rp = 0; rp < 16; rp += 2) {
            const int dp = ((rp & 3) >> 1) + 4 * (rp >> 2) + 2 * hi;
            u32 w0 = pb[(size_t)dp * NN];
            u32 w1 = pb[(size_t)(dp + 16) * NN];
            On0[rp]     += bf2f((us)(w0 & 0xFFFFu));
            On0[rp + 1] += bf2f((us)(w0 >> 16));
            On1[rp]     += bf2f((us)(w1 & 0xFFFFu));
            On1[rp + 1] += bf2f((us)(w1 >> 16));
        }
    }
    float gL = 0.f;
    #pragma unroll
    for (int i = 0; i < 4; ++i) gL += Lb[(size_t)(i * NB + b) * NN + q];
    const float rl2 = 1.0f / gL;
    #pragma unroll
    for (int i = 0; i < 16; ++i) { On0[i] *= rl2; On1[i] *= rl2; }

    short8 Bf[8];
    {
        uint4v w0, w1, w2, w3;
        w0[0] = cvtpk(On0[0], On0[1]);   w0[1] = cvtpk(On0[2], On0[3]);
        w0[2] = cvtpk(On0[4], On0[5]);   w0[3] = cvtpk(On0[6], On0[7]);
        w1[0] = cvtpk(On0[8], On0[9]);   w1[1] = cvtpk(On0[10], On0[11]);
        w1[2] = cvtpk(On0[12], On0[13]); w1[3] = cvtpk(On0[14], On0[15]);
        w2[0] = cvtpk(On1[0], On1[1]);   w2[1] = cvtpk(On1[2], On1[3]);
        w2[2] = cvtpk(On1[4], On1[5]);   w2[3] = cvtpk(On1[6], On1[7]);
        w3[0] = cvtpk(On1[8], On1[9]);   w3[1] = cvtpk(On1[10], On1[11]);
        w3[2] = cvtpk(On1[12], On1[13]); w3[3] = cvtpk(On1[14], On1[15]);
        Bf[0] = __builtin_bit_cast(short8, w0);
        Bf[1] = __builtin_bit_cast(short8, w1);
        Bf[2] = __builtin_bit_cast(short8, w2);
        Bf[3] = __builtin_bit_cast(short8, w3);
    }
    const us* xrow = Xbt + (size_t)(b * NN + q) * ND;
    #pragma unroll
    for (int c4 = 0; c4 < 4; ++c4)
        Bf[4 + c4] = comb(*(const short4v*)(xrow + c4 * 16 + hi * 4),
                          *(const short4v*)(xrow + c4 * 16 + hi * 4 + 8));

    f32x16 acc0, acc1;
    #pragma unroll
    for (int rq = 0; rq < 4; ++rq) {
        f32x4 b0 = *(const f32x4*)&bo[rq * 8 + hi * 4];
        f32x4 b1 = *(const f32x4*)&bo[32 + rq * 8 + hi * 4];
        #pragma unroll
        for (int j = 0; j < 4; ++j) { acc0[rq * 4 + j] = b0[j]; acc1[rq * 4 + j] = b1[j]; }
    }
    const us* wr0 = Wob + (size_t)ln * 128;
    const us* wr1 = Wob + (size_t)(32 + ln) * 128;
    #pragma unroll
    for (int kc = 0; kc < 8; ++kc) {
        short8 wf0 = comb(*(const short4v*)(wr0 + kc * 16 + hi * 4),
                          *(const short4v*)(wr0 + kc * 16 + hi * 4 + 8));
        short8 wf1 = comb(*(const short4v*)(wr1 + kc * 16 + hi * 4),
                          *(const short4v*)(wr1 + kc * 16 + hi * 4 + 8));
        acc0 = __builtin_amdgcn_mfma_f32_32x32x16_bf16(wf0, Bf[kc], acc0, 0, 0, 0);
        acc1 = __builtin_amdgcn_mfma_f32_32x32x16_bf16(wf1, Bf[kc], acc1, 0, 0, 0);
    }
    #pragma unroll
    for (int r = 0; r < 16; ++r) {
        const int od = (r & 3) + 8 * (r >> 2) + 4 * hi;
        out[((size_t)b * 64 + od) * NN + q] = acc0[r];
        out[((size_t)b * 64 + 32 + od) * NN + q] = acc1[r];
    }
}

extern "C" void kernel_launch(void* const* d_in, const int* in_sizes, int n_in,
                              void* d_out, int out_size, void* d_ws, size_t ws_size,
                              hipStream_t stream) {
    (void)in_sizes; (void)n_in; (void)out_size; (void)ws_size;
    const float* x  = (const float*)d_in[0];
    const float* Wq = (const float*)d_in[1];
    const float* bq = (const float*)d_in[2];
    const float* Wk = (const float*)d_in[3];
    const float* bk = (const float*)d_in[4];
    const float* Wv = (const float*)d_in[5];
    const float* bv = (const float*)d_in[6];
    const float* Wo = (const float*)d_in[7];
    const float* bo = (const float*)d_in[8];
    const int* ord  = (const int*)d_in[9];
    float* out = (float*)d_out;

    // ws: Qt,Kt,Vm,Xbt (8MB) + Wob 16KB + Opk 8MB (u32 pairs) + Lb 256KB + W*b 24KB ~= 16.3MB
    us* Qt  = (us*)d_ws;
    us* Kt  = Qt  + (size_t)NB * NN * ND;
    us* Vm  = Kt  + (size_t)NB * NN * ND;
    us* Xbt = Vm  + (size_t)NB * NN * ND;
    us* Wob = Xbt + (size_t)NB * NN * ND;
    u32* Opk = (u32*)(Wob + ND * (ND + NC));
    float* Lb = (float*)(Opk + (size_t)16 * 32 * NN);
    us* Wqb = (us*)(Lb + (size_t)4 * NB * NN);
    us* Wkb = Wqb + 4096;
    us* Wvb = Wkb + 4096;

    cvt_kernel<<<dim3(80), dim3(256), 0, stream>>>(Wo, Wq, Wk, Wv, Wob, Wqb, Wkb, Wvb);
    proj_kernel<<<dim3(NB * 64), dim3(256), 0, stream>>>(
        x, Wqb, bq, Wkb, bk, Wvb, bv, Qt, Kt, Vm, Xbt);
    attn_kernel<<<dim3(512), dim3(256), 0, stream>>>(Qt, Kt, Vm, ord, Opk, Lb);
    combine_kernel<<<dim3(512), dim3(64), 0, stream>>>(Opk, Lb, Xbt, Wob, bo, out);
}

// Round 16
// 53.075 us; speedup vs baseline: 1.3066x; 1.3066x over previous
//
#include <hip/hip_runtime.h>

typedef __attribute__((ext_vector_type(8))) short short8;
typedef __attribute__((ext_vector_type(4))) short short4v;
typedef __attribute__((ext_vector_type(4))) float f32x4;
typedef __attribute__((ext_vector_type(16))) float f32x16;
typedef __attribute__((ext_vector_type(4))) unsigned int uint4v;
typedef __attribute__((ext_vector_type(2))) unsigned int uint2v;
typedef unsigned short us;
typedef unsigned int u32;

#define NB 4
#define NC 64
#define NN 4096
#define ND 64
#define LOG2E 1.44269504088896340736f

static __device__ __forceinline__ us f2bf(float x) {
    u32 u = __builtin_bit_cast(u32, x);
    u += 0x7FFFu + ((u >> 16) & 1u);
    return (us)(u >> 16);
}

static __device__ __forceinline__ float bf2f(us v) {
    u32 u = ((u32)v) << 16;
    return __builtin_bit_cast(float, u);
}

static __device__ __forceinline__ u32 cvtpk(float a, float b) {
    u32 r;
    asm("v_cvt_pk_bf16_f32 %0, %1, %2" : "=v"(r) : "v"(a), "v"(b));
    return r;
}

static __device__ __forceinline__ short8 comb(short4v a, short4v b) {
    short8 r;
    r[0] = a[0]; r[1] = a[1]; r[2] = a[2]; r[3] = a[3];
    r[4] = b[0]; r[5] = b[1]; r[6] = b[2]; r[7] = b[3];
    return r;
}

static __device__ __forceinline__ void async_copy16(void* lds, const void* g) {
    __builtin_amdgcn_global_load_lds(
        (const __attribute__((address_space(1))) u32*)g,
        (__attribute__((address_space(3))) u32*)lds, 16, 0, 0);
}

static __device__ __forceinline__ int swz8(int row) {
    return (row & 7) ^ ((row >> 3) & 3);
}

// ---------------- kernel 1: weights -> bf16 (Wq pre-scaled by log2 e) ----------------
__global__ void cvt_kernel(const float* __restrict__ Wo,
                           const float* __restrict__ Wq,
                           const float* __restrict__ Wk,
                           const float* __restrict__ Wv,
                           us* __restrict__ Wob, us* __restrict__ Wqb,
                           us* __restrict__ Wkb, us* __restrict__ Wvb) {
    int i = blockIdx.x * 256 + threadIdx.x;
    if (i < 8192) Wob[i] = f2bf(Wo[i]);
    else if (i < 12288) Wqb[i - 8192] = f2bf(Wq[i - 8192] * LOG2E);
    else if (i < 16384) Wkb[i - 12288] = f2bf(Wk[i - 12288]);
    else if (i < 20480) Wvb[i - 16384] = f2bf(Wv[i - 16384]);
}

// ---------------- kernel 2: projections via MFMA (single-pass: Q,K,V,Xbt per block) ----------------
__global__ __launch_bounds__(256) void proj_kernel(
    const float* __restrict__ x,
    const us* __restrict__ Wqb, const float* __restrict__ bq,
    const us* __restrict__ Wkb, const float* __restrict__ bk,
    const us* __restrict__ Wvb, const float* __restrict__ bv,
    us* __restrict__ Qt, us* __restrict__ Kt,
    us* __restrict__ Vm, us* __restrict__ Xbt)
{
    __shared__ float xs[64][64];                 // [c][n] fp32
    __shared__ __align__(16) us xT[64][64];      // [n][c] bf16, XOR-swizzled
    const int t = threadIdx.x;
    const int v = blockIdx.x;
    const int b = v >> 6;
    const int n0 = (v & 63) << 6;
    const float* xb = x + (size_t)b * NC * NN + n0;
    #pragma unroll
    for (int i = 0; i < 4; ++i) {
        int s = t + i * 256;
        int c = s >> 4, col = (s & 15) << 2;
        *(f32x4*)&xs[c][col] = *(const f32x4*)&xb[(size_t)c * NN + col];
    }
    __syncthreads();
    {
        int n = t & 63, cg = t >> 6;
        int c0 = cg << 4;
        u32 pk[8];
        #pragma unroll
        for (int j = 0; j < 8; ++j) {
            float a0 = xs[c0 + 2 * j][n], a1 = xs[c0 + 2 * j + 1][n];
            pk[j] = (u32)f2bf(a0) | ((u32)f2bf(a1) << 16);
        }
        int b0 = (cg * 2) ^ (n & 7), b1 = (cg * 2 + 1) ^ (n & 7);
        *(uint4v*)&xT[n][b0 * 8] = (uint4v){pk[0], pk[1], pk[2], pk[3]};
        *(uint4v*)&xT[n][b1 * 8] = (uint4v){pk[4], pk[5], pk[6], pk[7]};
        us* dst = Xbt + (size_t)(b * NN + n0 + n) * ND + c0;
        *(uint4v*)dst       = (uint4v){pk[0], pk[1], pk[2], pk[3]};
        *(uint4v*)(dst + 8) = (uint4v){pk[4], pk[5], pk[6], pk[7]};
    }
    __syncthreads();
    const int w = t >> 6, l = t & 63, h = l >> 4, ln = l & 15;
    const int row = w * 16 + ln;
    short8 xq0 = *(const short8*)&xT[row][((h ^ (row & 7)) << 3)];
    short8 xq1 = *(const short8*)&xT[row][(((4 + h) ^ (row & 7)) << 3)];

    #pragma unroll
    for (int p = 0; p < 2; ++p) {
        const us* Wb = p ? Wkb : Wqb;
        const float* bias = p ? bk : bq;
        const float sc = p ? 1.0f : LOG2E;
        us* outp = p ? Kt : Qt;
        #pragma unroll
        for (int di = 0; di < 4; ++di) {
            const int d = di * 16 + ln;
            const us* wrb = Wb + (size_t)d * 64;
            short8 a0 = *(const short8*)(wrb + h * 8);
            short8 a1 = *(const short8*)(wrb + 32 + h * 8);
            f32x4 acc = *(const f32x4*)(bias + di * 16 + h * 4);
            acc *= sc;
            acc = __builtin_amdgcn_mfma_f32_16x16x32_bf16(a0, xq0, acc, 0, 0, 0);
            acc = __builtin_amdgcn_mfma_f32_16x16x32_bf16(a1, xq1, acc, 0, 0, 0);
            u32 lo = (u32)f2bf(acc[0]) | ((u32)f2bf(acc[1]) << 16);
            u32 hi2 = (u32)f2bf(acc[2]) | ((u32)f2bf(acc[3]) << 16);
            *(uint2v*)(outp + (size_t)(b * NN + n0 + row) * ND + di * 16 + h * 4) = (uint2v){lo, hi2};
        }
    }
    #pragma unroll
    for (int di = 0; di < 4; ++di) {
        const int d = di * 16 + ln;
        const us* wrb = Wvb + (size_t)d * 64;
        short8 a0 = *(const short8*)(wrb + h * 8);
        short8 a1 = *(const short8*)(wrb + 32 + h * 8);
        f32x4 acc = *(const f32x4*)(bv + di * 16 + h * 4);
        acc = __builtin_amdgcn_mfma_f32_16x16x32_bf16(a0, xq0, acc, 0, 0, 0);
        acc = __builtin_amdgcn_mfma_f32_16x16x32_bf16(a1, xq1, acc, 0, 0, 0);
        us* vp = Vm + (size_t)(b * ND + di * 16 + h * 4) * NN + n0 + row;
        vp[0] = f2bf(acc[0]); vp[NN] = f2bf(acc[1]);
        vp[2 * NN] = f2bf(acc[2]); vp[3 * NN] = f2bf(acc[3]);
    }
}

// ---------------- kernel 3: flash attention partials (r10-exact: 128-q blocks, 2-buf) ----------------
static __device__ __forceinline__ void mask_bounds32(int pt, int n032, int ng,
    int& lo_n, int& hi_n, int& lo_min, int& lo_max, int& hi_min, int& hi_max)
{
    if (pt == 0)      { lo_n = 0;           hi_n = ng;          lo_min = 0;              lo_max = 0;             hi_min = n032;           hi_max = n032 + 31; }
    else if (pt == 1) { lo_n = NN - 1 - ng; hi_n = NN - 1;      lo_min = NN - 32 - n032; lo_max = NN - 1 - n032; hi_min = NN - 1;         hi_max = NN - 1; }
    else if (pt == 2) { lo_n = ng;          hi_n = NN - 1;      lo_min = n032;           lo_max = n032 + 31;     hi_min = NN - 1;         hi_max = NN - 1; }
    else if (pt == 3) { lo_n = 0;           hi_n = NN - 1 - ng; lo_min = 0;              lo_max = 0;             hi_min = NN - 32 - n032; hi_max = NN - 1 - n032; }
    else              { lo_n = 0;           hi_n = NN - 1;      lo_min = 0;              lo_max = 0;             hi_min = NN - 1;         hi_max = NN - 1; }
}

__global__ __launch_bounds__(512, 4) void attn_kernel(
    const us* __restrict__ Qt, const us* __restrict__ Kt,
    const us* __restrict__ Vm,
    const int* __restrict__ ordp,
    u32* __restrict__ Opk, float* __restrict__ Lb)
{
    // 32KB: K [2 bufs][64m x 64d], V [2 bufs][64d x 64m]; swz8 16B-block swizzle
    __shared__ __align__(16) us Kl[2][64 * 64];
    __shared__ __align__(16) us Vl[2][64 * 64];
    __shared__ float cL[128];

    const int tid = threadIdx.x;
    const int w = tid >> 6, l = tid & 63;
    const int hi = l >> 5, ln = l & 31;
    const int nh = w & 3, mh = w >> 2;            // 4 q-quarters x 2 m-halves, shared tile
    const int bid = blockIdx.x;
    const int vid = (bid & 7) * 64 + (bid >> 3);  // bijective XCD swizzle (512 = 8*64)
    const int b = vid >> 7;
    const int ms = (vid >> 5) & 3;                // block-level m-quarter
    const int qt = vid & 31;
    const int n0 = qt << 7;                       // 128-q block tile
    const int mbase = ms << 10;                   // 1024-m quarter
    const int n032 = n0 + nh * 32;
    const int ng = n032 + ln;

    const int ord = ordp[0];
    int pt = 4;
    if (ord == 1) pt = 0;
    else if (ord == 2 || ord == 3) pt = 1;
    else if (ord == 4 || ord == 5 || ord == 8) pt = 2;
    else if (ord == 6 || ord == 7) pt = 3;
    int lo_n, hi_n, lo_min, lo_max, hi_min, hi_max;
    mask_bounds32(pt, n032, ng, lo_n, hi_n, lo_min, lo_max, hi_min, hi_max);

    const us* kb = Kt + (size_t)b * NN * ND;
    const us* vb = Vm + (size_t)b * ND * NN;
    const us* qrow = Qt + (size_t)(b * NN + n032 + ln) * ND;
    short8 qf0 = *(const short8*)(qrow + 0 * 16 + hi * 8);
    short8 qf1 = *(const short8*)(qrow + 1 * 16 + hi * 8);
    short8 qf2 = *(const short8*)(qrow + 2 * 16 + hi * 8);
    short8 qf3 = *(const short8*)(qrow + 3 * 16 + hi * 8);

    f32x16 O0, O1, Z;
    #pragma unroll
    for (int i = 0; i < 16; ++i) { O0[i] = 0.f; O1[i] = 0.f; Z[i] = 0.f; }
    float Lp = 0.f;

    // staging: waves 0-3 stage K (16 rows each), waves 4-7 stage V (16 d-rows each).
    // 2 async_copy16 calls (2KB) per wave per tile; unconditional (uniform vmcnt).
    auto stage = [&](int buf, int t) {
        const int m_base = mbase + t * 64;
        if (w < 4) {
            #pragma unroll
            for (int r = 0; r < 2; ++r) {
                const int rl = w * 16 + r * 8 + (l >> 3);
                const int blk = l & 7;
                const us* src = kb + (size_t)(m_base + rl) * ND + ((blk ^ swz8(rl)) << 3);
                async_copy16(&Kl[buf][(w * 16 + r * 8) * 64], src);
            }
        } else {
            #pragma unroll
            for (int r = 0; r < 2; ++r) {
                const int rl = (w - 4) * 16 + r * 8 + (l >> 3);
                const int blk = l & 7;
                const us* src = vb + (size_t)rl * NN + m_base + ((blk ^ swz8(rl)) << 3);
                async_copy16(&Vl[buf][((w - 4) * 16 + r * 8) * 64], src);
            }
        }
    };

    stage(0, 0);
    for (int t = 0; t < 16; ++t) {
        if (t < 15) {
            stage((t + 1) & 1, t + 1);
            asm volatile("s_waitcnt vmcnt(2)" ::: "memory");
        } else {
            asm volatile("s_waitcnt vmcnt(0)" ::: "memory");
        }
        __builtin_amdgcn_s_barrier();
        __builtin_amdgcn_sched_barrier(0);

        const us* KT = Kl[t & 1];
        const us* VT = Vl[t & 1];
        const int m0s = mbase + t * 64 + mh * 32;
        const bool skip = (m0s + 31 < lo_min) || (m0s > hi_max);
        const bool full = (m0s >= lo_max) && (m0s + 31 <= hi_min);

        __builtin_amdgcn_s_setprio(1);
        {
            const int row = mh * 32 + ln;
            const int rs = swz8(row);
            short8 a0 = *(const short8*)&KT[row * 64 + (((0 + hi) ^ rs) << 3)];
            short8 a1 = *(const short8*)&KT[row * 64 + (((2 + hi) ^ rs) << 3)];
            short8 a2 = *(const short8*)&KT[row * 64 + (((4 + hi) ^ rs) << 3)];
            short8 a3 = *(const short8*)&KT[row * 64 + (((6 + hi) ^ rs) << 3)];
            f32x16 st = __builtin_amdgcn_mfma_f32_32x32x16_bf16(a0, qf0, Z, 0, 0, 0);
            st = __builtin_amdgcn_mfma_f32_32x32x16_bf16(a1, qf1, st, 0, 0, 0);
            st = __builtin_amdgcn_mfma_f32_32x32x16_bf16(a2, qf2, st, 0, 0, 0);
            st = __builtin_amdgcn_mfma_f32_32x32x16_bf16(a3, qf3, st, 0, 0, 0);

            float p[16];
            float lp0 = 0.f, lp1 = 0.f;
            #pragma unroll
            for (int r = 0; r < 16; ++r) {
                p[r] = __builtin_amdgcn_exp2f(st[r]);  // no max-subtraction: |logit| small
                if (r & 1) lp1 += p[r]; else lp0 += p[r];
            }
            Lp += lp0 + lp1;
            if (!skip) {
                if (!full) {
                    #pragma unroll
                    for (int r = 0; r < 16; ++r) {
                        const int mg = m0s + (r & 3) + 8 * (r >> 2) + 4 * hi;
                        if (mg < lo_n || mg > hi_n) p[r] = 0.f;
                    }
                }
                #pragma unroll
                for (int c16 = 0; c16 < 2; ++c16) {
                    uint4v pw;
                    pw[0] = cvtpk(p[c16 * 8 + 0], p[c16 * 8 + 1]);
                    pw[1] = cvtpk(p[c16 * 8 + 2], p[c16 * 8 + 3]);
                    pw[2] = cvtpk(p[c16 * 8 + 4], p[c16 * 8 + 5]);
                    pw[3] = cvtpk(p[c16 * 8 + 6], p[c16 * 8 + 7]);
                    short8 pb = __builtin_bit_cast(short8, pw);
                    const int blkA = mh * 4 + c16 * 2;
                    {
                        const int rv = ln, rvs = swz8(rv);
                        short4v va  = *(const short4v*)&VT[rv * 64 + ((blkA ^ rvs) << 3) + hi * 4];
                        short4v vb2 = *(const short4v*)&VT[rv * 64 + (((blkA + 1) ^ rvs) << 3) + hi * 4];
                        O0 = __builtin_amdgcn_mfma_f32_32x32x16_bf16(comb(va, vb2), pb, O0, 0, 0, 0);
                    }
                    {
                        const int rv = 32 + ln, rvs = swz8(rv);
                        short4v va  = *(const short4v*)&VT[rv * 64 + ((blkA ^ rvs) << 3) + hi * 4];
                        short4v vb2 = *(const short4v*)&VT[rv * 64 + (((blkA + 1) ^ rvs) << 3) + hi * 4];
                        O1 = __builtin_amdgcn_mfma_f32_32x32x16_bf16(comb(va, vb2), pb, O1, 0, 0, 0);
                    }
                }
            }
        }
        __builtin_amdgcn_s_setprio(0);
        __builtin_amdgcn_sched_barrier(0);
        __builtin_amdgcn_s_barrier();
    }

    // ---- in-block combine across mh (L additive; no max-tracking) ----
    float Lw = Lp + __shfl_xor(Lp, 32);

    // cO: per-nh 32q x 64d f32 = 8KB; nh 0,1 in Kl region (16KB), nh 2,3 in Vl region
    float* cO = (nh < 2 ? (float*)&Kl[0][0] : (float*)&Vl[0][0]) + (nh & 1) * 2048;
    if (mh == 1) {
        float* dsto = cO + ln * 64;
        #pragma unroll
        for (int rq = 0; rq < 4; ++rq) {
            f32x4 s0, s1;
            #pragma unroll
            for (int j = 0; j < 4; ++j) { s0[j] = O0[rq * 4 + j]; s1[j] = O1[rq * 4 + j]; }
            *(f32x4*)&dsto[rq * 8 + hi * 4] = s0;
            *(f32x4*)&dsto[32 + rq * 8 + hi * 4] = s1;
        }
        if (hi == 0) cL[nh * 32 + ln] = Lw;
    }
    __syncthreads();
    if (mh == 1) return;

    const float gL = Lw + cL[nh * 32 + ln];
    const float* sp = cO + ln * 64;
    f32x16 On0 = O0, On1 = O1;
    #pragma unroll
    for (int rq = 0; rq < 4; ++rq) {
        f32x4 a = *(const f32x4*)&sp[rq * 8 + hi * 4];
        f32x4 c = *(const f32x4*)&sp[32 + rq * 8 + hi * 4];
        #pragma unroll
        for (int j = 0; j < 4; ++j) { On0[rq * 4 + j] += a[j]; On1[rq * 4 + j] += c[j]; }
    }

    // write unnormalized bf16-pair-packed partials: Opk [4 ms][B][32 dpair][N] u32
    u32* opk = Opk + ((size_t)(ms * NB + b) * 32) * NN + n032 + ln;
    #pragma unroll
    for (int rp = 0; rp < 16; rp += 2) {
        const int dp = ((rp & 3) >> 1) + 4 * (rp >> 2) + 2 * hi;   // d0(rp)/2
        opk[(size_t)dp * NN] = cvtpk(On0[rp], On0[rp + 1]);
        opk[(size_t)(dp + 16) * NN] = cvtpk(On1[rp], On1[rp + 1]);
    }
    if (hi == 0) Lb[(size_t)(ms * NB + b) * NN + n032 + ln] = gL;
}

// ---------------- kernel 4: combine partials + fused output conv (512 x 1-wave) ----------------
__global__ __launch_bounds__(64) void combine_kernel(
    const u32* __restrict__ Opk, const float* __restrict__ Lb,
    const us* __restrict__ Xbt, const us* __restrict__ Wob,
    const float* __restrict__ bo, float* __restrict__ out)
{
    const int l = threadIdx.x, hi = l >> 5, ln = l & 31;
    const int gw = blockIdx.x;
    const int b = gw >> 7;
    const int n032 = (gw & 127) << 5;
    const int q = n032 + ln;

    f32x16 On0, On1;
    #pragma unroll
    for (int i = 0; i < 16; ++i) { On0[i] = 0.f; On1[i] = 0.f; }
    #pragma unroll
    for (int part = 0; part < 4; ++part) {
        const u32* pb = Opk + ((size_t)(part * NB + b) * 32) * NN + q;
        #pragma unroll
        for (int rp = 0; rp < 16; rp += 2) {
            const int dp = ((rp & 3) >> 1) + 4 * (rp >> 2) + 2 * hi;
            u32 w0 = pb[(size_t)dp * NN];
            u32 w1 = pb[(size_t)(dp + 16) * NN];
            On0[rp]     += bf2f((us)(w0 & 0xFFFFu));
            On0[rp + 1] += bf2f((us)(w0 >> 16));
            On1[rp]     += bf2f((us)(w1 & 0xFFFFu));
            On1[rp + 1] += bf2f((us)(w1 >> 16));
        }
    }
    float gL = 0.f;
    #pragma unroll
    for (int i = 0; i < 4; ++i) gL += Lb[(size_t)(i * NB + b) * NN + q];
    const float rl2 = 1.0f / gL;
    #pragma unroll
    for (int i = 0; i < 16; ++i) { On0[i] *= rl2; On1[i] *= rl2; }

    short8 Bf[8];
    {
        uint4v w0, w1, w2, w3;
        w0[0] = cvtpk(On0[0], On0[1]);   w0[1] = cvtpk(On0[2], On0[3]);
        w0[2] = cvtpk(On0[4], On0[5]);   w0[3] = cvtpk(On0[6], On0[7]);
        w1[0] = cvtpk(On0[8], On0[9]);   w1[1] = cvtpk(On0[10], On0[11]);
        w1[2] = cvtpk(On0[12], On0[13]); w1[3] = cvtpk(On0[14], On0[15]);
        w2[0] = cvtpk(On1[0], On1[1]);   w2[1] = cvtpk(On1[2], On1[3]);
        w2[2] = cvtpk(On1[4], On1[5]);   w2[3] = cvtpk(On1[6], On1[7]);
        w3[0] = cvtpk(On1[8], On1[9]);   w3[1] = cvtpk(On1[10], On1[11]);
        w3[2] = cvtpk(On1[12], On1[13]); w3[3] = cvtpk(On1[14], On1[15]);
        Bf[0] = __builtin_bit_cast(short8, w0);
        Bf[1] = __builtin_bit_cast(short8, w1);
        Bf[2] = __builtin_bit_cast(short8, w2);
        Bf[3] = __builtin_bit_cast(short8, w3);
    }
    const us* xrow = Xbt + (size_t)(b * NN + q) * ND;
    #pragma unroll
    for (int c4 = 0; c4 < 4; ++c4)
        Bf[4 + c4] = comb(*(const short4v*)(xrow + c4 * 16 + hi * 4),
                          *(const short4v*)(xrow + c4 * 16 + hi * 4 + 8));

    f32x16 acc0, acc1;
    #pragma unroll
    for (int rq = 0; rq < 4; ++rq) {
        f32x4 b0 = *(const f32x4*)&bo[rq * 8 + hi * 4];
        f32x4 b1 = *(const f32x4*)&bo[32 + rq * 8 + hi * 4];
        #pragma unroll
        for (int j = 0; j < 4; ++j) { acc0[rq * 4 + j] = b0[j]; acc1[rq * 4 + j] = b1[j]; }
    }
    const us* wr0 = Wob + (size_t)ln * 128;
    const us* wr1 = Wob + (size_t)(32 + ln) * 128;
    #pragma unroll
    for (int kc = 0; kc < 8; ++kc) {
        short8 wf0 = comb(*(const short4v*)(wr0 + kc * 16 + hi * 4),
                          *(const short4v*)(wr0 + kc * 16 + hi * 4 + 8));
        short8 wf1 = comb(*(const short4v*)(wr1 + kc * 16 + hi * 4),
                          *(const short4v*)(wr1 + kc * 16 + hi * 4 + 8));
        acc0 = __builtin_amdgcn_mfma_f32_32x32x16_bf16(wf0, Bf[kc], acc0, 0, 0, 0);
        acc1 = __builtin_amdgcn_mfma_f32_32x32x16_bf16(wf1, Bf[kc], acc1, 0, 0, 0);
    }
    #pragma unroll
    for (int r = 0; r < 16; ++r) {
        const int od = (r & 3) + 8 * (r >> 2) + 4 * hi;
        out[((size_t)b * 64 + od) * NN + q] = acc0[r];
        out[((size_t)b * 64 + 32 + od) * NN + q] = acc1[r];
    }
}

extern "C" void kernel_launch(void* const* d_in, const int* in_sizes, int n_in,
                              void* d_out, int out_size, void* d_ws, size_t ws_size,
                              hipStream_t stream) {
    (void)in_sizes; (void)n_in; (void)out_size; (void)ws_size;
    const float* x  = (const float*)d_in[0];
    const float* Wq = (const float*)d_in[1];
    const float* bq = (const float*)d_in[2];
    const float* Wk = (const float*)d_in[3];
    const float* bk = (const float*)d_in[4];
    const float* Wv = (const float*)d_in[5];
    const float* bv = (const float*)d_in[6];
    const float* Wo = (const float*)d_in[7];
    const float* bo = (const float*)d_in[8];
    const int* ord  = (const int*)d_in[9];
    float* out = (float*)d_out;

    // ws: Qt,Kt,Vm,Xbt (8MB) + Wob 16KB + Opk 8MB (u32 pairs) + Lb 256KB + W*b 24KB ~= 16.3MB
    us* Qt  = (us*)d_ws;
    us* Kt  = Qt  + (size_t)NB * NN * ND;
    us* Vm  = Kt  + (size_t)NB * NN * ND;
    us* Xbt = Vm  + (size_t)NB * NN * ND;
    us* Wob = Xbt + (size_t)NB * NN * ND;
    u32* Opk = (u32*)(Wob + ND * (ND + NC));
    float* Lb = (float*)(Opk + (size_t)16 * 32 * NN);
    us* Wqb = (us*)(Lb + (size_t)4 * NB * NN);
    us* Wkb = Wqb + 4096;
    us* Wvb = Wkb + 4096;

    cvt_kernel<<<dim3(80), dim3(256), 0, stream>>>(Wo, Wq, Wk, Wv, Wob, Wqb, Wkb, Wvb);
    proj_kernel<<<dim3(NB * 64), dim3(256), 0, stream>>>(
        x, Wqb, bq, Wkb, bk, Wvb, bv, Qt, Kt, Vm, Xbt);
    attn_kernel<<<dim3(512), dim3(512), 0, stream>>>(Qt, Kt, Vm, ord, Opk, Lb);
    combine_kernel<<<dim3(512), dim3(64), 0, stream>>>(Opk, Lb, Xbt, Wob, bo, out);
}

// Round 17
// 50.535 us; speedup vs baseline: 1.3722x; 1.0503x over previous
//
#include <hip/hip_runtime.h>

typedef __attribute__((ext_vector_type(8))) short short8;
typedef __attribute__((ext_vector_type(4))) short short4v;
typedef __attribute__((ext_vector_type(4))) float f32x4;
typedef __attribute__((ext_vector_type(16))) float f32x16;
typedef __attribute__((ext_vector_type(4))) unsigned int uint4v;
typedef __attribute__((ext_vector_type(2))) unsigned int uint2v;
typedef unsigned short us;
typedef unsigned int u32;

#define NB 4
#define NC 64
#define NN 4096
#define ND 64
#define LOG2E 1.44269504088896340736f

static __device__ __forceinline__ us f2bf(float x) {
    u32 u = __builtin_bit_cast(u32, x);
    u += 0x7FFFu + ((u >> 16) & 1u);
    return (us)(u >> 16);
}

static __device__ __forceinline__ float bf2f(us v) {
    u32 u = ((u32)v) << 16;
    return __builtin_bit_cast(float, u);
}

static __device__ __forceinline__ u32 cvtpk(float a, float b) {
    u32 r;
    asm("v_cvt_pk_bf16_f32 %0, %1, %2" : "=v"(r) : "v"(a), "v"(b));
    return r;
}

static __device__ __forceinline__ short8 comb(short4v a, short4v b) {
    short8 r;
    r[0] = a[0]; r[1] = a[1]; r[2] = a[2]; r[3] = a[3];
    r[4] = b[0]; r[5] = b[1]; r[6] = b[2]; r[7] = b[3];
    return r;
}

static __device__ __forceinline__ void async_copy16(void* lds, const void* g) {
    __builtin_amdgcn_global_load_lds(
        (const __attribute__((address_space(1))) u32*)g,
        (__attribute__((address_space(3))) u32*)lds, 16, 0, 0);
}

static __device__ __forceinline__ int swz8(int row) {
    return (row & 7) ^ ((row >> 3) & 3);
}

// ---------------- kernel 1: projections via MFMA (single-pass; inline f32->bf16 weights) ----------------
__global__ __launch_bounds__(256) void proj_kernel(
    const float* __restrict__ x,
    const float* __restrict__ Wq, const float* __restrict__ bq,
    const float* __restrict__ Wk, const float* __restrict__ bk,
    const float* __restrict__ Wv, const float* __restrict__ bv,
    const float* __restrict__ Wo,
    us* __restrict__ Qt, us* __restrict__ Kt,
    us* __restrict__ Vm, us* __restrict__ Xbt, us* __restrict__ Wob)
{
    __shared__ float xs[64][64];                 // [c][n] fp32
    __shared__ __align__(16) us xT[64][64];      // [n][c] bf16, XOR-swizzled
    const int t = threadIdx.x;
    const int v = blockIdx.x;
    const int b = v >> 6;
    const int n0 = (v & 63) << 6;
    const float* xb = x + (size_t)b * NC * NN + n0;
    #pragma unroll
    for (int i = 0; i < 4; ++i) {
        int s = t + i * 256;
        int c = s >> 4, col = (s & 15) << 2;
        *(f32x4*)&xs[c][col] = *(const f32x4*)&xb[(size_t)c * NN + col];
    }
    __syncthreads();
    {
        int n = t & 63, cg = t >> 6;
        int c0 = cg << 4;
        u32 pk[8];
        #pragma unroll
        for (int j = 0; j < 8; ++j) {
            float a0 = xs[c0 + 2 * j][n], a1 = xs[c0 + 2 * j + 1][n];
            pk[j] = (u32)f2bf(a0) | ((u32)f2bf(a1) << 16);
        }
        int b0 = (cg * 2) ^ (n & 7), b1 = (cg * 2 + 1) ^ (n & 7);
        *(uint4v*)&xT[n][b0 * 8] = (uint4v){pk[0], pk[1], pk[2], pk[3]};
        *(uint4v*)&xT[n][b1 * 8] = (uint4v){pk[4], pk[5], pk[6], pk[7]};
        us* dst = Xbt + (size_t)(b * NN + n0 + n) * ND + c0;
        *(uint4v*)dst       = (uint4v){pk[0], pk[1], pk[2], pk[3]};
        *(uint4v*)(dst + 8) = (uint4v){pk[4], pk[5], pk[6], pk[7]};
    }
    __syncthreads();
    const int w = t >> 6, l = t & 63, h = l >> 4, ln = l & 15;
    const int row = w * 16 + ln;
    short8 xq0 = *(const short8*)&xT[row][((h ^ (row & 7)) << 3)];
    short8 xq1 = *(const short8*)&xT[row][(((4 + h) ^ (row & 7)) << 3)];

    #pragma unroll
    for (int p = 0; p < 2; ++p) {
        const float* W = p ? Wk : Wq;
        const float* bias = p ? bk : bq;
        const float sc = p ? 1.0f : LOG2E;
        us* outp = p ? Kt : Qt;
        #pragma unroll
        for (int di = 0; di < 4; ++di) {
            const int d = di * 16 + ln;
            const float* wr = W + (size_t)d * 64;
            short8 a0, a1;
            f32x4 f0 = *(const f32x4*)(wr + h * 8);
            f32x4 f1 = *(const f32x4*)(wr + h * 8 + 4);
            f32x4 f2 = *(const f32x4*)(wr + 32 + h * 8);
            f32x4 f3 = *(const f32x4*)(wr + 32 + h * 8 + 4);
            #pragma unroll
            for (int j = 0; j < 4; ++j) {
                a0[j] = (short)f2bf(f0[j] * sc); a0[4 + j] = (short)f2bf(f1[j] * sc);
                a1[j] = (short)f2bf(f2[j] * sc); a1[4 + j] = (short)f2bf(f3[j] * sc);
            }
            f32x4 acc = *(const f32x4*)(bias + di * 16 + h * 4);
            acc *= sc;
            acc = __builtin_amdgcn_mfma_f32_16x16x32_bf16(a0, xq0, acc, 0, 0, 0);
            acc = __builtin_amdgcn_mfma_f32_16x16x32_bf16(a1, xq1, acc, 0, 0, 0);
            u32 lo = (u32)f2bf(acc[0]) | ((u32)f2bf(acc[1]) << 16);
            u32 hi2 = (u32)f2bf(acc[2]) | ((u32)f2bf(acc[3]) << 16);
            *(uint2v*)(outp + (size_t)(b * NN + n0 + row) * ND + di * 16 + h * 4) = (uint2v){lo, hi2};
        }
    }
    #pragma unroll
    for (int di = 0; di < 4; ++di) {
        const int d = di * 16 + ln;
        const float* wr = Wv + (size_t)d * 64;
        short8 a0, a1;
        f32x4 f0 = *(const f32x4*)(wr + h * 8);
        f32x4 f1 = *(const f32x4*)(wr + h * 8 + 4);
        f32x4 f2 = *(const f32x4*)(wr + 32 + h * 8);
        f32x4 f3 = *(const f32x4*)(wr + 32 + h * 8 + 4);
        #pragma unroll
        for (int j = 0; j < 4; ++j) {
            a0[j] = (short)f2bf(f0[j]); a0[4 + j] = (short)f2bf(f1[j]);
            a1[j] = (short)f2bf(f2[j]); a1[4 + j] = (short)f2bf(f3[j]);
        }
        f32x4 acc = *(const f32x4*)(bv + di * 16 + h * 4);
        acc = __builtin_amdgcn_mfma_f32_16x16x32_bf16(a0, xq0, acc, 0, 0, 0);
        acc = __builtin_amdgcn_mfma_f32_16x16x32_bf16(a1, xq1, acc, 0, 0, 0);
        us* vp = Vm + (size_t)(b * ND + di * 16 + h * 4) * NN + n0 + row;
        vp[0] = f2bf(acc[0]); vp[NN] = f2bf(acc[1]);
        vp[2 * NN] = f2bf(acc[2]); vp[3 * NN] = f2bf(acc[3]);
    }
    // block 0 converts Wo -> bf16 for the (later) combine kernel
    if (v == 0) {
        #pragma unroll
        for (int i = 0; i < 32; ++i) Wob[t + i * 256] = f2bf(Wo[t + i * 256]);
    }
}

// ---------------- kernel 2: flash attention partials (r10/r16-exact) ----------------
static __device__ __forceinline__ void mask_bounds32(int pt, int n032, int ng,
    int& lo_n, int& hi_n, int& lo_min, int& lo_max, int& hi_min, int& hi_max)
{
    if (pt == 0)      { lo_n = 0;           hi_n = ng;          lo_min = 0;              lo_max = 0;             hi_min = n032;           hi_max = n032 + 31; }
    else if (pt == 1) { lo_n = NN - 1 - ng; hi_n = NN - 1;      lo_min = NN - 32 - n032; lo_max = NN - 1 - n032; hi_min = NN - 1;         hi_max = NN - 1; }
    else if (pt == 2) { lo_n = ng;          hi_n = NN - 1;      lo_min = n032;           lo_max = n032 + 31;     hi_min = NN - 1;         hi_max = NN - 1; }
    else if (pt == 3) { lo_n = 0;           hi_n = NN - 1 - ng; lo_min = 0;              lo_max = 0;             hi_min = NN - 32 - n032; hi_max = NN - 1 - n032; }
    else              { lo_n = 0;           hi_n = NN - 1;      lo_min = 0;              lo_max = 0;             hi_min = NN - 1;         hi_max = NN - 1; }
}

__global__ __launch_bounds__(512, 4) void attn_kernel(
    const us* __restrict__ Qt, const us* __restrict__ Kt,
    const us* __restrict__ Vm,
    const int* __restrict__ ordp,
    u32* __restrict__ Opk, float* __restrict__ Lb)
{
    // 32KB: K [2 bufs][64m x 64d], V [2 bufs][64d x 64m]; swz8 16B-block swizzle
    __shared__ __align__(16) us Kl[2][64 * 64];
    __shared__ __align__(16) us Vl[2][64 * 64];
    __shared__ float cL[128];

    const int tid = threadIdx.x;
    const int w = tid >> 6, l = tid & 63;
    const int hi = l >> 5, ln = l & 31;
    const int nh = w & 3, mh = w >> 2;            // 4 q-quarters x 2 m-halves, shared tile
    const int bid = blockIdx.x;
    const int vid = (bid & 7) * 64 + (bid >> 3);  // bijective XCD swizzle (512 = 8*64)
    const int b = vid >> 7;
    const int ms = (vid >> 5) & 3;                // block-level m-quarter
    const int qt = vid & 31;
    const int n0 = qt << 7;                       // 128-q block tile
    const int mbase = ms << 10;                   // 1024-m quarter
    const int n032 = n0 + nh * 32;
    const int ng = n032 + ln;

    const int ord = ordp[0];
    int pt = 4;
    if (ord == 1) pt = 0;
    else if (ord == 2 || ord == 3) pt = 1;
    else if (ord == 4 || ord == 5 || ord == 8) pt = 2;
    else if (ord == 6 || ord == 7) pt = 3;
    int lo_n, hi_n, lo_min, lo_max, hi_min, hi_max;
    mask_bounds32(pt, n032, ng, lo_n, hi_n, lo_min, lo_max, hi_min, hi_max);

    const us* kb = Kt + (size_t)b * NN * ND;
    const us* vb = Vm + (size_t)b * ND * NN;
    const us* qrow = Qt + (size_t)(b * NN + n032 + ln) * ND;
    short8 qf0 = *(const short8*)(qrow + 0 * 16 + hi * 8);
    short8 qf1 = *(const short8*)(qrow + 1 * 16 + hi * 8);
    short8 qf2 = *(const short8*)(qrow + 2 * 16 + hi * 8);
    short8 qf3 = *(const short8*)(qrow + 3 * 16 + hi * 8);

    f32x16 O0, O1, Z;
    #pragma unroll
    for (int i = 0; i < 16; ++i) { O0[i] = 0.f; O1[i] = 0.f; Z[i] = 0.f; }
    float Lp = 0.f;

    // staging: waves 0-3 stage K (16 rows each), waves 4-7 stage V (16 d-rows each).
    // 2 async_copy16 calls (2KB) per wave per tile; unconditional (uniform vmcnt).
    auto stage = [&](int buf, int t) {
        const int m_base = mbase + t * 64;
        if (w < 4) {
            #pragma unroll
            for (int r = 0; r < 2; ++r) {
                const int rl = w * 16 + r * 8 + (l >> 3);
                const int blk = l & 7;
                const us* src = kb + (size_t)(m_base + rl) * ND + ((blk ^ swz8(rl)) << 3);
                async_copy16(&Kl[buf][(w * 16 + r * 8) * 64], src);
            }
        } else {
            #pragma unroll
            for (int r = 0; r < 2; ++r) {
                const int rl = (w - 4) * 16 + r * 8 + (l >> 3);
                const int blk = l & 7;
                const us* src = vb + (size_t)rl * NN + m_base + ((blk ^ swz8(rl)) << 3);
                async_copy16(&Vl[buf][((w - 4) * 16 + r * 8) * 64], src);
            }
        }
    };

    stage(0, 0);
    for (int t = 0; t < 16; ++t) {
        if (t < 15) {
            stage((t + 1) & 1, t + 1);
            asm volatile("s_waitcnt vmcnt(2)" ::: "memory");
        } else {
            asm volatile("s_waitcnt vmcnt(0)" ::: "memory");
        }
        __builtin_amdgcn_s_barrier();
        __builtin_amdgcn_sched_barrier(0);

        const us* KT = Kl[t & 1];
        const us* VT = Vl[t & 1];
        const int m0s = mbase + t * 64 + mh * 32;
        const bool skip = (m0s + 31 < lo_min) || (m0s > hi_max);
        const bool full = (m0s >= lo_max) && (m0s + 31 <= hi_min);

        __builtin_amdgcn_s_setprio(1);
        {
            const int row = mh * 32 + ln;
            const int rs = swz8(row);
            short8 a0 = *(const short8*)&KT[row * 64 + (((0 + hi) ^ rs) << 3)];
            short8 a1 = *(const short8*)&KT[row * 64 + (((2 + hi) ^ rs) << 3)];
            short8 a2 = *(const short8*)&KT[row * 64 + (((4 + hi) ^ rs) << 3)];
            short8 a3 = *(const short8*)&KT[row * 64 + (((6 + hi) ^ rs) << 3)];
            f32x16 st = __builtin_amdgcn_mfma_f32_32x32x16_bf16(a0, qf0, Z, 0, 0, 0);
            st = __builtin_amdgcn_mfma_f32_32x32x16_bf16(a1, qf1, st, 0, 0, 0);
            st = __builtin_amdgcn_mfma_f32_32x32x16_bf16(a2, qf2, st, 0, 0, 0);
            st = __builtin_amdgcn_mfma_f32_32x32x16_bf16(a3, qf3, st, 0, 0, 0);

            float p[16];
            float lp0 = 0.f, lp1 = 0.f;
            #pragma unroll
            for (int r = 0; r < 16; ++r) {
                p[r] = __builtin_amdgcn_exp2f(st[r]);  // no max-subtraction: |logit| small
                if (r & 1) lp1 += p[r]; else lp0 += p[r];
            }
            Lp += lp0 + lp1;
            if (!skip) {
                if (!full) {
                    #pragma unroll
                    for (int r = 0; r < 16; ++r) {
                        const int mg = m0s + (r & 3) + 8 * (r >> 2) + 4 * hi;
                        if (mg < lo_n || mg > hi_n) p[r] = 0.f;
                    }
                }
                #pragma unroll
                for (int c16 = 0; c16 < 2; ++c16) {
                    uint4v pw;
                    pw[0] = cvtpk(p[c16 * 8 + 0], p[c16 * 8 + 1]);
                    pw[1] = cvtpk(p[c16 * 8 + 2], p[c16 * 8 + 3]);
                    pw[2] = cvtpk(p[c16 * 8 + 4], p[c16 * 8 + 5]);
                    pw[3] = cvtpk(p[c16 * 8 + 6], p[c16 * 8 + 7]);
                    short8 pb = __builtin_bit_cast(short8, pw);
                    const int blkA = mh * 4 + c16 * 2;
                    {
                        const int rv = ln, rvs = swz8(rv);
                        short4v va  = *(const short4v*)&VT[rv * 64 + ((blkA ^ rvs) << 3) + hi * 4];
                        short4v vb2 = *(const short4v*)&VT[rv * 64 + (((blkA + 1) ^ rvs) << 3) + hi * 4];
                        O0 = __builtin_amdgcn_mfma_f32_32x32x16_bf16(comb(va, vb2), pb, O0, 0, 0, 0);
                    }
                    {
                        const int rv = 32 + ln, rvs = swz8(rv);
                        short4v va  = *(const short4v*)&VT[rv * 64 + ((blkA ^ rvs) << 3) + hi * 4];
                        short4v vb2 = *(const short4v*)&VT[rv * 64 + (((blkA + 1) ^ rvs) << 3) + hi * 4];
                        O1 = __builtin_amdgcn_mfma_f32_32x32x16_bf16(comb(va, vb2), pb, O1, 0, 0, 0);
                    }
                }
            }
        }
        __builtin_amdgcn_s_setprio(0);
        __builtin_amdgcn_sched_barrier(0);
        __builtin_amdgcn_s_barrier();
    }

    // ---- in-block combine across mh (L additive; no max-tracking) ----
    float Lw = Lp + __shfl_xor(Lp, 32);

    // cO: per-nh 32q x 64d f32 = 8KB; nh 0,1 in Kl region (16KB), nh 2,3 in Vl region
    float* cO = (nh < 2 ? (float*)&Kl[0][0] : (float*)&Vl[0][0]) + (nh & 1) * 2048;
    if (mh == 1) {
        float* dsto = cO + ln * 64;
        #pragma unroll
        for (int rq = 0; rq < 4; ++rq) {
            f32x4 s0, s1;
            #pragma unroll
            for (int j = 0; j < 4; ++j) { s0[j] = O0[rq * 4 + j]; s1[j] = O1[rq * 4 + j]; }
            *(f32x4*)&dsto[rq * 8 + hi * 4] = s0;
            *(f32x4*)&dsto[32 + rq * 8 + hi * 4] = s1;
        }
        if (hi == 0) cL[nh * 32 + ln] = Lw;
    }
    __syncthreads();
    if (mh == 1) return;

    const float gL = Lw + cL[nh * 32 + ln];
    const float* sp = cO + ln * 64;
    f32x16 On0 = O0, On1 = O1;
    #pragma unroll
    for (int rq = 0; rq < 4; ++rq) {
        f32x4 a = *(const f32x4*)&sp[rq * 8 + hi * 4];
        f32x4 c = *(const f32x4*)&sp[32 + rq * 8 + hi * 4];
        #pragma unroll
        for (int j = 0; j < 4; ++j) { On0[rq * 4 + j] += a[j]; On1[rq * 4 + j] += c[j]; }
    }

    // write unnormalized bf16-pair-packed partials: Opk [4 ms][B][32 dpair][N] u32
    u32* opk = Opk + ((size_t)(ms * NB + b) * 32) * NN + n032 + ln;
    #pragma unroll
    for (int rp = 0; rp < 16; rp += 2) {
        const int dp = ((rp & 3) >> 1) + 4 * (rp >> 2) + 2 * hi;   // d0(rp)/2
        opk[(size_t)dp * NN] = cvtpk(On0[rp], On0[rp + 1]);
        opk[(size_t)(dp + 16) * NN] = cvtpk(On1[rp], On1[rp + 1]);
    }
    if (hi == 0) Lb[(size_t)(ms * NB + b) * NN + n032 + ln] = gL;
}

// ---------------- kernel 3: combine partials + fused output conv (512 x 1-wave) ----------------
__global__ __launch_bounds__(64) void combine_kernel(
    const u32* __restrict__ Opk, const float* __restrict__ Lb,
    const us* __restrict__ Xbt, const us* __restrict__ Wob,
    const float* __restrict__ bo, float* __restrict__ out)
{
    const int l = threadIdx.x, hi = l >> 5, ln = l & 31;
    const int gw = blockIdx.x;
    const int b = gw >> 7;
    const int n032 = (gw & 127) << 5;
    const int q = n032 + ln;

    f32x16 On0, On1;
    #pragma unroll
    for (int i = 0; i < 16; ++i) { On0[i] = 0.f; On1[i] = 0.f; }
    #pragma unroll
    for (int part = 0; part < 4; ++part) {
        const u32* pb = Opk + ((size_t)(part * NB + b) * 32) * NN + q;
        #pragma unroll
        for (int rp = 0; rp < 16; rp += 2) {
            const int dp = ((rp & 3) >> 1) + 4 * (rp >> 2) + 2 * hi;
            u32 w0 = pb[(size_t)dp * NN];
            u32 w1 = pb[(size_t)(dp + 16) * NN];
            On0[rp]     += bf2f((us)(w0 & 0xFFFFu));
            On0[rp + 1] += bf2f((us)(w0 >> 16));
            On1[rp]     += bf2f((us)(w1 & 0xFFFFu));
            On1[rp + 1] += bf2f((us)(w1 >> 16));
        }
    }
    float gL = 0.f;
    #pragma unroll
    for (int i = 0; i < 4; ++i) gL += Lb[(size_t)(i * NB + b) * NN + q];
    const float rl2 = 1.0f / gL;
    #pragma unroll
    for (int i = 0; i < 16; ++i) { On0[i] *= rl2; On1[i] *= rl2; }

    short8 Bf[8];
    {
        uint4v w0, w1, w2, w3;
        w0[0] = cvtpk(On0[0], On0[1]);   w0[1] = cvtpk(On0[2], On0[3]);
        w0[2] = cvtpk(On0[4], On0[5]);   w0[3] = cvtpk(On0[6], On0[7]);
        w1[0] = cvtpk(On0[8], On0[9]);   w1[1] = cvtpk(On0[10], On0[11]);
        w1[2] = cvtpk(On0[12], On0[13]); w1[3] = cvtpk(On0[14], On0[15]);
        w2[0] = cvtpk(On1[0], On1[1]);   w2[1] = cvtpk(On1[2], On1[3]);
        w2[2] = cvtpk(On1[4], On1[5]);   w2[3] = cvtpk(On1[6], On1[7]);
        w3[0] = cvtpk(On1[8], On1[9]);   w3[1] = cvtpk(On1[10], On1[11]);
        w3[2] = cvtpk(On1[12], On1[13]); w3[3] = cvtpk(On1[14], On1[15]);
        Bf[0] = __builtin_bit_cast(short8, w0);
        Bf[1] = __builtin_bit_cast(short8, w1);
        Bf[2] = __builtin_bit_cast(short8, w2);
        Bf[3] = __builtin_bit_cast(short8, w3);
    }
    const us* xrow = Xbt + (size_t)(b * NN + q) * ND;
    #pragma unroll
    for (int c4 = 0; c4 < 4; ++c4)
        Bf[4 + c4] = comb(*(const short4v*)(xrow + c4 * 16 + hi * 4),
                          *(const short4v*)(xrow + c4 * 16 + hi * 4 + 8));

    f32x16 acc0, acc1;
    #pragma unroll
    for (int rq = 0; rq < 4; ++rq) {
        f32x4 b0 = *(const f32x4*)&bo[rq * 8 + hi * 4];
        f32x4 b1 = *(const f32x4*)&bo[32 + rq * 8 + hi * 4];
        #pragma unroll
        for (int j = 0; j < 4; ++j) { acc0[rq * 4 + j] = b0[j]; acc1[rq * 4 + j] = b1[j]; }
    }
    const us* wr0 = Wob + (size_t)ln * 128;
    const us* wr1 = Wob + (size_t)(32 + ln) * 128;
    #pragma unroll
    for (int kc = 0; kc < 8; ++kc) {
        short8 wf0 = comb(*(const short4v*)(wr0 + kc * 16 + hi * 4),
                          *(const short4v*)(wr0 + kc * 16 + hi * 4 + 8));
        short8 wf1 = comb(*(const short4v*)(wr1 + kc * 16 + hi * 4),
                          *(const short4v*)(wr1 + kc * 16 + hi * 4 + 8));
        acc0 = __builtin_amdgcn_mfma_f32_32x32x16_bf16(wf0, Bf[kc], acc0, 0, 0, 0);
        acc1 = __builtin_amdgcn_mfma_f32_32x32x16_bf16(wf1, Bf[kc], acc1, 0, 0, 0);
    }
    #pragma unroll
    for (int r = 0; r < 16; ++r) {
        const int od = (r & 3) + 8 * (r >> 2) + 4 * hi;
        out[((size_t)b * 64 + od) * NN + q] = acc0[r];
        out[((size_t)b * 64 + 32 + od) * NN + q] = acc1[r];
    }
}

extern "C" void kernel_launch(void* const* d_in, const int* in_sizes, int n_in,
                              void* d_out, int out_size, void* d_ws, size_t ws_size,
                              hipStream_t stream) {
    (void)in_sizes; (void)n_in; (void)out_size; (void)ws_size;
    const float* x  = (const float*)d_in[0];
    const float* Wq = (const float*)d_in[1];
    const float* bq = (const float*)d_in[2];
    const float* Wk = (const float*)d_in[3];
    const float* bk = (const float*)d_in[4];
    const float* Wv = (const float*)d_in[5];
    const float* bv = (const float*)d_in[6];
    const float* Wo = (const float*)d_in[7];
    const float* bo = (const float*)d_in[8];
    const int* ord  = (const int*)d_in[9];
    float* out = (float*)d_out;

    // ws: Qt,Kt,Vm,Xbt (8MB) + Wob 16KB + Opk 8MB (u32 pairs) + Lb 256KB ~= 16.3MB
    us* Qt  = (us*)d_ws;
    us* Kt  = Qt  + (size_t)NB * NN * ND;
    us* Vm  = Kt  + (size_t)NB * NN * ND;
    us* Xbt = Vm  + (size_t)NB * NN * ND;
    us* Wob = Xbt + (size_t)NB * NN * ND;
    u32* Opk = (u32*)(Wob + ND * (ND + NC));
    float* Lb = (float*)(Opk + (size_t)16 * 32 * NN);

    proj_kernel<<<dim3(NB * 64), dim3(256), 0, stream>>>(
        x, Wq, bq, Wk, bk, Wv, bv, Wo, Qt, Kt, Vm, Xbt, Wob);
    attn_kernel<<<dim3(512), dim3(512), 0, stream>>>(Qt, Kt, Vm, ord, Opk, Lb);
    combine_kernel<<<dim3(512), dim3(64), 0, stream>>>(Opk, Lb, Xbt, Wob, bo, out);
}